// Round 9
// baseline (263.981 us; speedup 1.0000x reference)
//
#include <hip/hip_runtime.h>
#include <hip/hip_bf16.h>

#define E 1024
#define DK 64
#define SEQ 4096
#define NB 4
// 0.125 * log2(e): scores arrive pre-multiplied so softmax = exp2(s) = v_exp_f32
#define KSCALE 0.18033688011112042f

typedef short bf16x8 __attribute__((ext_vector_type(8)));
typedef short bf16x4 __attribute__((ext_vector_type(4)));
typedef float f32x4 __attribute__((ext_vector_type(4)));

__device__ inline unsigned short f2bf(float f) {
    unsigned int u = __float_as_uint(f);
    u += 0x7fff + ((u >> 16) & 1);   // round-to-nearest-even
    return (unsigned short)(u >> 16);
}
__device__ inline unsigned int cvtpk(float a, float b) {
    union { __hip_bfloat162 h; unsigned int u; } x;
    x.h = __float22bfloat162_rn(make_float2(a, b));
    return x.u;
}
__device__ inline bf16x8 cvt8(f32x4 a, f32x4 b) {
    union { unsigned int u[4]; bf16x8 v; } x;
    x.u[0] = cvtpk(a[0], a[1]); x.u[1] = cvtpk(a[2], a[3]);
    x.u[2] = cvtpk(b[0], b[1]); x.u[3] = cvtpk(b[2], b[3]);
    return x.v;
}

// ---------------- Kernel 0: W [1024][64] fp32 -> Wt [64][1024] bf16 (LDS transpose) --------
__global__ __launch_bounds__(256) void wt_kernel(
    const float* __restrict__ Wq, const float* __restrict__ Wk, const float* __restrict__ Wv,
    unsigned short* __restrict__ wtq, unsigned short* __restrict__ wtk, unsigned short* __restrict__ wtv)
{
    const float* src; unsigned short* dst;
    if (blockIdx.y == 0)      { src = Wq; dst = wtq; }
    else if (blockIdx.y == 1) { src = Wk; dst = wtk; }
    else                      { src = Wv; dst = wtv; }
    const int tid = threadIdx.x;
    const int e0 = blockIdx.x * 64;
    __shared__ float Ws[64][65];
    #pragma unroll
    for (int i = 0; i < 4; ++i) {
        int flat = i * 256 + tid;
        int r = flat >> 4;
        int c4 = (flat & 15) << 2;
        float4 v = *reinterpret_cast<const float4*>(&src[(size_t)(e0 + r) * DK + c4]);
        Ws[c4 + 0][r] = v.x; Ws[c4 + 1][r] = v.y; Ws[c4 + 2][r] = v.z; Ws[c4 + 3][r] = v.w;
    }
    __syncthreads();
    #pragma unroll
    for (int i = 0; i < 4; ++i) {
        int flat = i * 256 + tid;
        int c = flat >> 4;
        int r4 = (flat & 15) << 2;
        ushort4 o;
        o.x = f2bf(Ws[c][r4 + 0]); o.y = f2bf(Ws[c][r4 + 1]);
        o.z = f2bf(Ws[c][r4 + 2]); o.w = f2bf(Ws[c][r4 + 3]);
        *reinterpret_cast<ushort4*>(&dst[(size_t)c * E + e0 + r4]) = o;
    }
}

// ---------------- Kernel 1: QKV projection — register-only, barrier-free ----------------
// grid (256, 2), 256 threads. Wave w owns A rows w*16..+16 (register prefetch 1 kb ahead);
// W^T fragments read directly from L2-hot global each iter. No LDS, no __syncthreads.
// y==0: Q = in2@Wq + bq ; y==1: K = (in1@Wk + bk)*KSCALE ; V = in1@Wv + bv (transposed).
__global__ __launch_bounds__(256) void proj_kernel(
    const float* __restrict__ in_q, const float* __restrict__ in_kv,
    const unsigned short* __restrict__ wtq, const unsigned short* __restrict__ wtk,
    const unsigned short* __restrict__ wtv,
    const float* __restrict__ bq, const float* __restrict__ bk, const float* __restrict__ bv,
    unsigned short* __restrict__ Qw, unsigned short* __restrict__ Kw, unsigned short* __restrict__ Vtw)
{
    const int tid = threadIdx.x;
    const int w = tid >> 6, lane = tid & 63, quad = lane >> 4, l16 = lane & 15;
    const int row0 = blockIdx.x * 64;
    const bool isQ = (blockIdx.y == 0);
    const float* Arow = (isQ ? in_q : in_kv) + (size_t)(row0 + w * 16 + l16) * E;
    const unsigned short* w0 = isQ ? wtq : wtk;

    f32x4 acc0[4] = {};
    f32x4 acc1[4] = {};

    // prologue: A regs for kb=0 (each lane: 2 ks x 2 f32x4 = 32B)
    f32x4 a_cur[4];
    #pragma unroll
    for (int ks = 0; ks < 2; ++ks)
        #pragma unroll
        for (int j = 0; j < 2; ++j)
            a_cur[ks * 2 + j] = *reinterpret_cast<const f32x4*>(Arow + ks * 32 + quad * 8 + j * 4);

    for (int kb = 0; kb < 16; ++kb) {
        f32x4 a_nxt[4];
        if (kb < 15) {
            const float* an = Arow + (kb + 1) * 64;
            #pragma unroll
            for (int ks = 0; ks < 2; ++ks)
                #pragma unroll
                for (int j = 0; j < 2; ++j)
                    a_nxt[ks * 2 + j] = *reinterpret_cast<const f32x4*>(an + ks * 32 + quad * 8 + j * 4);
        }
        #pragma unroll
        for (int ks = 0; ks < 2; ++ks) {
            bf16x8 af = cvt8(a_cur[ks * 2], a_cur[ks * 2 + 1]);
            const int ko = kb * 64 + ks * 32 + quad * 8;
            #pragma unroll
            for (int ct = 0; ct < 4; ++ct) {
                bf16x8 b0 = *reinterpret_cast<const bf16x8*>(&w0[(size_t)(ct * 16 + l16) * E + ko]);
                acc0[ct] = __builtin_amdgcn_mfma_f32_16x16x32_bf16(af, b0, acc0[ct], 0, 0, 0);
                if (!isQ) {
                    bf16x8 b1 = *reinterpret_cast<const bf16x8*>(&wtv[(size_t)(ct * 16 + l16) * E + ko]);
                    acc1[ct] = __builtin_amdgcn_mfma_f32_16x16x32_bf16(af, b1, acc1[ct], 0, 0, 0);
                }
            }
        }
        #pragma unroll
        for (int j = 0; j < 4; ++j) a_cur[j] = a_nxt[j];
    }

    // epilogue: C/D layout col=lane&15, row=quad*4+reg
    const int orow0 = row0 + w * 16 + quad * 4;
    #pragma unroll
    for (int ct = 0; ct < 4; ++ct) {
        int col = ct * 16 + l16;
        if (isQ) {
            float bias = bq[col];
            #pragma unroll
            for (int r = 0; r < 4; ++r)
                Qw[(size_t)(orow0 + r) * DK + col] = f2bf(acc0[ct][r] + bias);
        } else {
            float biask = bk[col], biasv = bv[col];
            #pragma unroll
            for (int r = 0; r < 4; ++r) {
                int grow = orow0 + r;
                Kw[(size_t)grow * DK + col] = f2bf((acc0[ct][r] + biask) * KSCALE);
                int bb = grow >> 12;
                int tok = grow & 4095;
                Vtw[((size_t)(bb * 64 + col)) * SEQ + tok] = f2bf(acc1[ct][r] + biasv);
            }
        }
    }
}

// ---------------- Kernel 2: flash attention — register-direct, barrier-free main loop ----
// grid 256 x 512 threads (8 waves). Wave w: key-slice (w&3)*16, tile parity w>>2 -> 32 iters
// over 64-key tiles. K/V fragments loaded straight to registers, one tile ahead (precise
// vmcnt). S^T C-layout feeds PV 16x16x16 B-operand directly. v_exp_f32 (scale pre-folded).
__global__ __launch_bounds__(512) void attn_kernel(
    const unsigned short* __restrict__ Qw, const unsigned short* __restrict__ Kw,
    const unsigned short* __restrict__ Vtw, float* __restrict__ out)
{
    const int tid = threadIdx.x;
    const int w = tid >> 6, lane = tid & 63, quad = lane >> 4, l16 = lane & 15;
    const int wk = w & 3, wp = w >> 2;
    const int b = (blockIdx.x & 7) >> 1;                       // XCD-aware: 2 MB K/V per XCD
    const int qt = ((blockIdx.x >> 3) << 1) | (blockIdx.x & 1);

    __shared__ float LDSf[8][2][16][68];   // 69.6 KB (reduce only)
    __shared__ float LDSl[8][4][16];

    // Q as B-fragments (loop-invariant): B[k=d][n=q]
    bf16x8 qfb[2][4];
    #pragma unroll
    for (int ks = 0; ks < 2; ++ks)
        #pragma unroll
        for (int ct = 0; ct < 4; ++ct)
            qfb[ks][ct] = *reinterpret_cast<const bf16x8*>(
                &Qw[((size_t)(b * SEQ + qt * 64 + ct * 16 + l16)) * DK + ks * 32 + quad * 8]);

    // per-lane base pointers
    const unsigned short* Kp = Kw + ((size_t)(b * SEQ) + wk * 16 + l16) * DK;
    const unsigned short* Vp[4];
    #pragma unroll
    for (int ct = 0; ct < 4; ++ct)
        Vp[ct] = Vtw + ((size_t)(b * 64 + ct * 16 + l16)) * SEQ + wk * 16 + quad * 4;

    // prologue: fragments for first tile (kt = wp)
    bf16x8 kf_c0 = *reinterpret_cast<const bf16x8*>(Kp + (size_t)wp * 64 * DK + quad * 8);
    bf16x8 kf_c1 = *reinterpret_cast<const bf16x8*>(Kp + (size_t)wp * 64 * DK + 32 + quad * 8);
    bf16x4 va_c[4];
    #pragma unroll
    for (int ct = 0; ct < 4; ++ct)
        va_c[ct] = *reinterpret_cast<const bf16x4*>(Vp[ct] + (size_t)wp * 64);

    float lp[4] = {0.f, 0.f, 0.f, 0.f};
    f32x4 o[4][4] = {};   // o[ct_d][ct_q]

    #pragma unroll 1
    for (int i = 0; i < 32; ++i) {
        // prefetch next tile's fragments into fresh registers
        bf16x8 kf_n0, kf_n1;
        bf16x4 va_n[4];
        if (i < 31) {
            const size_t koff = (size_t)(2 * (i + 1) + wp) * 64;
            kf_n0 = *reinterpret_cast<const bf16x8*>(Kp + koff * DK + quad * 8);
            kf_n1 = *reinterpret_cast<const bf16x8*>(Kp + koff * DK + 32 + quad * 8);
            #pragma unroll
            for (int ct = 0; ct < 4; ++ct)
                va_n[ct] = *reinterpret_cast<const bf16x4*>(Vp[ct] + koff);
        }

        // S^T = K @ Q^T : C row = key_local = quad*4+r, col = q = ct*16+l16
        f32x4 sacc[4] = {};
        #pragma unroll
        for (int ct = 0; ct < 4; ++ct) {
            sacc[ct] = __builtin_amdgcn_mfma_f32_16x16x32_bf16(kf_c0, qfb[0][ct], sacc[ct], 0, 0, 0);
            sacc[ct] = __builtin_amdgcn_mfma_f32_16x16x32_bf16(kf_c1, qfb[1][ct], sacc[ct], 0, 0, 0);
        }

        // p = exp2(s) via v_exp_f32 (log2e folded into K scale); P^T is PV B-operand layout
        #pragma unroll
        for (int cq = 0; cq < 4; ++cq) {
            float p0 = __builtin_amdgcn_exp2f(sacc[cq][0]);
            float p1 = __builtin_amdgcn_exp2f(sacc[cq][1]);
            float p2 = __builtin_amdgcn_exp2f(sacc[cq][2]);
            float p3 = __builtin_amdgcn_exp2f(sacc[cq][3]);
            lp[cq] += (p0 + p1) + (p2 + p3);
            union { unsigned int u[2]; bf16x4 v; } pbu;
            pbu.u[0] = cvtpk(p0, p1);
            pbu.u[1] = cvtpk(p2, p3);
            bf16x4 pb = pbu.v;
            #pragma unroll
            for (int cd = 0; cd < 4; ++cd)
                o[cd][cq] = __builtin_amdgcn_mfma_f32_16x16x16bf16_1k(va_c[cd], pb, o[cd][cq], 0, 0, 0);
        }

        kf_c0 = kf_n0; kf_c1 = kf_n1;
        #pragma unroll
        for (int ct = 0; ct < 4; ++ct) va_c[ct] = va_n[ct];
    }

    // l: reduce across quads (wave's 16 keys), publish per wave
    #pragma unroll
    for (int cq = 0; cq < 4; ++cq) {
        float t = lp[cq];
        t += __shfl_xor(t, 16, 64);
        t += __shfl_xor(t, 32, 64);
        lp[cq] = t;
    }
    if (lane < 16)
        #pragma unroll
        for (int cq = 0; cq < 4; ++cq)
            LDSl[w][cq][lane] = lp[cq];

    // cross-wave O reduction + normalize + store: 2 rounds x 2 q-tiles (512 threads)
    #pragma unroll
    for (int rr = 0; rr < 2; ++rr) {
        #pragma unroll
        for (int hh = 0; hh < 2; ++hh)
            #pragma unroll
            for (int cd = 0; cd < 4; ++cd)
                *reinterpret_cast<f32x4*>(&LDSf[w][hh][l16][cd * 16 + quad * 4]) = o[cd][rr * 2 + hh];
        __syncthreads();
        {
            const int hh = tid >> 8;
            const int cq = rr * 2 + hh;
            const int ql = (tid >> 4) & 15;
            const int d4 = (tid & 15) << 2;
            f32x4 acc = {};
            #pragma unroll
            for (int w2 = 0; w2 < 8; ++w2)
                acc += *reinterpret_cast<const f32x4*>(&LDSf[w2][hh][ql][d4]);
            float lq = 0.f;
            #pragma unroll
            for (int w2 = 0; w2 < 8; ++w2)
                lq += LDSl[w2][cq][ql];
            f32x4 res = acc * (1.0f / lq);
            *reinterpret_cast<f32x4*>(&out[((size_t)(b * SEQ + qt * 64 + cq * 16 + ql)) * DK + d4]) = res;
        }
        __syncthreads();
    }
}

extern "C" void kernel_launch(void* const* d_in, const int* in_sizes, int n_in,
                              void* d_out, int out_size, void* d_ws, size_t ws_size,
                              hipStream_t stream) {
    const float* input1 = (const float*)d_in[0];
    const float* input2 = (const float*)d_in[1];
    const float* Wq = (const float*)d_in[2];
    const float* bq = (const float*)d_in[3];
    const float* Wk = (const float*)d_in[4];
    const float* bk = (const float*)d_in[5];
    const float* Wv = (const float*)d_in[6];
    const float* bv = (const float*)d_in[7];
    float* out = (float*)d_out;

    char* ws = (char*)d_ws;
    unsigned short* wtq = (unsigned short*)(ws + 0);
    unsigned short* wtk = (unsigned short*)(ws + 131072);
    unsigned short* wtv = (unsigned short*)(ws + 262144);
    unsigned short* Qw  = (unsigned short*)(ws + 393216);
    unsigned short* Kw  = (unsigned short*)(ws + 2490368);
    unsigned short* Vtw = (unsigned short*)(ws + 4587520);

    wt_kernel<<<dim3(16, 3), 256, 0, stream>>>(Wq, Wk, Wv, wtq, wtk, wtv);
    proj_kernel<<<dim3(256, 2), 256, 0, stream>>>(input2, input1, wtq, wtk, wtv,
                                                  bq, bk, bv, Qw, Kw, Vtw);
    attn_kernel<<<dim3(256), 512, 0, stream>>>(Qw, Kw, Vtw, out);
}

// Round 10
// 222.848 us; speedup vs baseline: 1.1846x; 1.1846x over previous
//
#include <hip/hip_runtime.h>
#include <hip/hip_bf16.h>

#define E 1024
#define DK 64
#define SEQ 4096
#define NB 4
// 0.125 * log2(e): scores arrive pre-multiplied so softmax = exp2(s) = v_exp_f32
#define KSCALE 0.18033688011112042f

typedef short bf16x8 __attribute__((ext_vector_type(8)));
typedef short bf16x4 __attribute__((ext_vector_type(4)));
typedef float f32x4 __attribute__((ext_vector_type(4)));

typedef const __attribute__((address_space(1))) unsigned int* gcp;
typedef __attribute__((address_space(3))) unsigned int* lcp;

__device__ inline unsigned short f2bf(float f) {
    unsigned int u = __float_as_uint(f);
    u += 0x7fff + ((u >> 16) & 1);   // round-to-nearest-even
    return (unsigned short)(u >> 16);
}
__device__ inline unsigned int cvtpk(float a, float b) {
    union { __hip_bfloat162 h; unsigned int u; } x;
    x.h = __float22bfloat162_rn(make_float2(a, b));
    return x.u;
}
__device__ inline bf16x8 cvt8(f32x4 a, f32x4 b) {
    union { unsigned int u[4]; bf16x8 v; } x;
    x.u[0] = cvtpk(a[0], a[1]); x.u[1] = cvtpk(a[2], a[3]);
    x.u[2] = cvtpk(b[0], b[1]); x.u[3] = cvtpk(b[2], b[3]);
    return x.v;
}

// ---------------- Kernel 0: W [1024][64] fp32 -> Wt [64][1024] bf16 (LDS transpose) --------
__global__ __launch_bounds__(256) void wt_kernel(
    const float* __restrict__ Wq, const float* __restrict__ Wk, const float* __restrict__ Wv,
    unsigned short* __restrict__ wtq, unsigned short* __restrict__ wtk, unsigned short* __restrict__ wtv)
{
    const float* src; unsigned short* dst;
    if (blockIdx.y == 0)      { src = Wq; dst = wtq; }
    else if (blockIdx.y == 1) { src = Wk; dst = wtk; }
    else                      { src = Wv; dst = wtv; }
    const int tid = threadIdx.x;
    const int e0 = blockIdx.x * 64;
    __shared__ float Ws[64][65];
    #pragma unroll
    for (int i = 0; i < 4; ++i) {
        int flat = i * 256 + tid;
        int r = flat >> 4;
        int c4 = (flat & 15) << 2;
        float4 v = *reinterpret_cast<const float4*>(&src[(size_t)(e0 + r) * DK + c4]);
        Ws[c4 + 0][r] = v.x; Ws[c4 + 1][r] = v.y; Ws[c4 + 2][r] = v.z; Ws[c4 + 3][r] = v.w;
    }
    __syncthreads();
    #pragma unroll
    for (int i = 0; i < 4; ++i) {
        int flat = i * 256 + tid;
        int c = flat >> 4;
        int r4 = (flat & 15) << 2;
        ushort4 o;
        o.x = f2bf(Ws[c][r4 + 0]); o.y = f2bf(Ws[c][r4 + 1]);
        o.z = f2bf(Ws[c][r4 + 2]); o.w = f2bf(Ws[c][r4 + 3]);
        *reinterpret_cast<ushort4*>(&dst[(size_t)c * E + e0 + r4]) = o;
    }
}

// ---------------- Kernel 1: QKV projection — A in registers, W via async LDS dbuf ---------
// grid (256, 2), 256 threads, 32 KB LDS -> 4-5 blocks/CU. Wave w owns A rows w*16..+16
// (register prefetch 1 kb ahead). W^T staged block-shared via global_load_lds width=16 with
// XOR chunk swizzle (phys = logical ^ (row&7)), double-buffered, one barrier per kb.
// y==0: Q = in2@Wq + bq ; y==1: K = (in1@Wk + bk)*KSCALE ; V = in1@Wv + bv (transposed).
__global__ __launch_bounds__(256, 4) void proj_kernel(
    const float* __restrict__ in_q, const float* __restrict__ in_kv,
    const unsigned short* __restrict__ wtq, const unsigned short* __restrict__ wtk,
    const unsigned short* __restrict__ wtv,
    const float* __restrict__ bq, const float* __restrict__ bk, const float* __restrict__ bv,
    unsigned short* __restrict__ Qw, unsigned short* __restrict__ Kw, unsigned short* __restrict__ Vtw)
{
    const int tid = threadIdx.x;
    const int w = tid >> 6, lane = tid & 63, quad = lane >> 4, l16 = lane & 15;
    const int row0 = blockIdx.x * 64;
    const bool isQ = (blockIdx.y == 0);
    const float* Arow = (isQ ? in_q : in_kv) + (size_t)(row0 + w * 16 + l16) * E;
    const unsigned short* w0 = isQ ? wtq : wtk;

    __shared__ unsigned short W0s[2][4096];   // 16 KB
    __shared__ unsigned short W1s[2][4096];   // 16 KB

    const int rl = lane >> 3, pp = lane & 7;

    // ---- prime: W tiles for kb=0 (async), A regs for kb=0 ----
    #pragma unroll
    for (int i = 0; i < 2; ++i) {
        int g = w * 2 + i;
        int r = g * 8 + rl;
        int lc = pp ^ (r & 7);
        __builtin_amdgcn_global_load_lds((gcp)(const void*)(w0 + (size_t)r * E + lc * 8),
                                         (lcp)(void*)&W0s[0][g * 512], 16, 0, 0);
        if (!isQ)
            __builtin_amdgcn_global_load_lds((gcp)(const void*)(wtv + (size_t)r * E + lc * 8),
                                             (lcp)(void*)&W1s[0][g * 512], 16, 0, 0);
    }
    f32x4 a_cur[4];
    #pragma unroll
    for (int ks = 0; ks < 2; ++ks)
        #pragma unroll
        for (int j = 0; j < 2; ++j)
            a_cur[ks * 2 + j] = *reinterpret_cast<const f32x4*>(Arow + ks * 32 + quad * 8 + j * 4);
    __syncthreads();

    f32x4 acc0[4] = {};
    f32x4 acc1[4] = {};

    for (int kb = 0; kb < 16; ++kb) {
        const int cur = kb & 1, nxt = cur ^ 1;
        f32x4 a_nxt[4];
        if (kb < 15) {
            const int ko = (kb + 1) * 64;
            // async W prefetch into the other buffer
            #pragma unroll
            for (int i = 0; i < 2; ++i) {
                int g = w * 2 + i;
                int r = g * 8 + rl;
                int lc = pp ^ (r & 7);
                __builtin_amdgcn_global_load_lds((gcp)(const void*)(w0 + (size_t)r * E + ko + lc * 8),
                                                 (lcp)(void*)&W0s[nxt][g * 512], 16, 0, 0);
                if (!isQ)
                    __builtin_amdgcn_global_load_lds((gcp)(const void*)(wtv + (size_t)r * E + ko + lc * 8),
                                                     (lcp)(void*)&W1s[nxt][g * 512], 16, 0, 0);
            }
            // A register prefetch
            const float* an = Arow + ko;
            #pragma unroll
            for (int ks = 0; ks < 2; ++ks)
                #pragma unroll
                for (int j = 0; j < 2; ++j)
                    a_nxt[ks * 2 + j] = *reinterpret_cast<const f32x4*>(an + ks * 32 + quad * 8 + j * 4);
        }
        // compute on cur
        #pragma unroll
        for (int ks = 0; ks < 2; ++ks) {
            bf16x8 af = cvt8(a_cur[ks * 2], a_cur[ks * 2 + 1]);
            #pragma unroll
            for (int ct = 0; ct < 4; ++ct) {
                int brow = ct * 16 + l16;
                int pc = (ks * 4 + quad) ^ (brow & 7);
                bf16x8 b0 = *reinterpret_cast<const bf16x8*>(&W0s[cur][brow * 64 + pc * 8]);
                acc0[ct] = __builtin_amdgcn_mfma_f32_16x16x32_bf16(af, b0, acc0[ct], 0, 0, 0);
                if (!isQ) {
                    bf16x8 b1 = *reinterpret_cast<const bf16x8*>(&W1s[cur][brow * 64 + pc * 8]);
                    acc1[ct] = __builtin_amdgcn_mfma_f32_16x16x32_bf16(af, b1, acc1[ct], 0, 0, 0);
                }
            }
        }
        #pragma unroll
        for (int j = 0; j < 4; ++j) a_cur[j] = a_nxt[j];
        if (kb < 15) __syncthreads();
    }

    // epilogue: C/D layout col=lane&15, row=quad*4+reg
    const int orow0 = row0 + w * 16 + quad * 4;
    #pragma unroll
    for (int ct = 0; ct < 4; ++ct) {
        int col = ct * 16 + l16;
        if (isQ) {
            float bias = bq[col];
            #pragma unroll
            for (int r = 0; r < 4; ++r)
                Qw[(size_t)(orow0 + r) * DK + col] = f2bf(acc0[ct][r] + bias);
        } else {
            float biask = bk[col], biasv = bv[col];
            #pragma unroll
            for (int r = 0; r < 4; ++r) {
                int grow = orow0 + r;
                Kw[(size_t)grow * DK + col] = f2bf((acc0[ct][r] + biask) * KSCALE);
                int bb = grow >> 12;
                int tok = grow & 4095;
                Vtw[((size_t)(bb * 64 + col)) * SEQ + tok] = f2bf(acc1[ct][r] + biasv);
            }
        }
    }
}

// ---------------- Kernel 2: flash attention — register-direct, barrier-free main loop ----
// grid 256 x 512 threads (8 waves). Wave w: key-slice (w&3)*16, tile parity w>>2 -> 32 iters
// over 64-key tiles. K/V fragments loaded straight to registers, one tile ahead (precise
// vmcnt). S^T C-layout feeds PV 16x16x16 B-operand directly. v_exp_f32 (scale pre-folded).
__global__ __launch_bounds__(512) void attn_kernel(
    const unsigned short* __restrict__ Qw, const unsigned short* __restrict__ Kw,
    const unsigned short* __restrict__ Vtw, float* __restrict__ out)
{
    const int tid = threadIdx.x;
    const int w = tid >> 6, lane = tid & 63, quad = lane >> 4, l16 = lane & 15;
    const int wk = w & 3, wp = w >> 2;
    const int b = (blockIdx.x & 7) >> 1;                       // XCD-aware: 2 MB K/V per XCD
    const int qt = ((blockIdx.x >> 3) << 1) | (blockIdx.x & 1);

    __shared__ float LDSf[8][2][16][68];   // 69.6 KB (reduce only)
    __shared__ float LDSl[8][4][16];

    // Q as B-fragments (loop-invariant): B[k=d][n=q]
    bf16x8 qfb[2][4];
    #pragma unroll
    for (int ks = 0; ks < 2; ++ks)
        #pragma unroll
        for (int ct = 0; ct < 4; ++ct)
            qfb[ks][ct] = *reinterpret_cast<const bf16x8*>(
                &Qw[((size_t)(b * SEQ + qt * 64 + ct * 16 + l16)) * DK + ks * 32 + quad * 8]);

    // per-lane base pointers
    const unsigned short* Kp = Kw + ((size_t)(b * SEQ) + wk * 16 + l16) * DK;
    const unsigned short* Vp[4];
    #pragma unroll
    for (int ct = 0; ct < 4; ++ct)
        Vp[ct] = Vtw + ((size_t)(b * 64 + ct * 16 + l16)) * SEQ + wk * 16 + quad * 4;

    // prologue: fragments for first tile (kt = wp)
    bf16x8 kf_c0 = *reinterpret_cast<const bf16x8*>(Kp + (size_t)wp * 64 * DK + quad * 8);
    bf16x8 kf_c1 = *reinterpret_cast<const bf16x8*>(Kp + (size_t)wp * 64 * DK + 32 + quad * 8);
    bf16x4 va_c[4];
    #pragma unroll
    for (int ct = 0; ct < 4; ++ct)
        va_c[ct] = *reinterpret_cast<const bf16x4*>(Vp[ct] + (size_t)wp * 64);

    float lp[4] = {0.f, 0.f, 0.f, 0.f};
    f32x4 o[4][4] = {};   // o[ct_d][ct_q]

    #pragma unroll 1
    for (int i = 0; i < 32; ++i) {
        // prefetch next tile's fragments into fresh registers
        bf16x8 kf_n0, kf_n1;
        bf16x4 va_n[4];
        if (i < 31) {
            const size_t koff = (size_t)(2 * (i + 1) + wp) * 64;
            kf_n0 = *reinterpret_cast<const bf16x8*>(Kp + koff * DK + quad * 8);
            kf_n1 = *reinterpret_cast<const bf16x8*>(Kp + koff * DK + 32 + quad * 8);
            #pragma unroll
            for (int ct = 0; ct < 4; ++ct)
                va_n[ct] = *reinterpret_cast<const bf16x4*>(Vp[ct] + koff);
        }

        // S^T = K @ Q^T : C row = key_local = quad*4+r, col = q = ct*16+l16
        f32x4 sacc[4] = {};
        #pragma unroll
        for (int ct = 0; ct < 4; ++ct) {
            sacc[ct] = __builtin_amdgcn_mfma_f32_16x16x32_bf16(kf_c0, qfb[0][ct], sacc[ct], 0, 0, 0);
            sacc[ct] = __builtin_amdgcn_mfma_f32_16x16x32_bf16(kf_c1, qfb[1][ct], sacc[ct], 0, 0, 0);
        }

        // p = exp2(s) via v_exp_f32 (log2e folded into K scale); P^T is PV B-operand layout
        #pragma unroll
        for (int cq = 0; cq < 4; ++cq) {
            float p0 = __builtin_amdgcn_exp2f(sacc[cq][0]);
            float p1 = __builtin_amdgcn_exp2f(sacc[cq][1]);
            float p2 = __builtin_amdgcn_exp2f(sacc[cq][2]);
            float p3 = __builtin_amdgcn_exp2f(sacc[cq][3]);
            lp[cq] += (p0 + p1) + (p2 + p3);
            union { unsigned int u[2]; bf16x4 v; } pbu;
            pbu.u[0] = cvtpk(p0, p1);
            pbu.u[1] = cvtpk(p2, p3);
            bf16x4 pb = pbu.v;
            #pragma unroll
            for (int cd = 0; cd < 4; ++cd)
                o[cd][cq] = __builtin_amdgcn_mfma_f32_16x16x16bf16_1k(va_c[cd], pb, o[cd][cq], 0, 0, 0);
        }

        kf_c0 = kf_n0; kf_c1 = kf_n1;
        #pragma unroll
        for (int ct = 0; ct < 4; ++ct) va_c[ct] = va_n[ct];
    }

    // l: reduce across quads (wave's 16 keys), publish per wave
    #pragma unroll
    for (int cq = 0; cq < 4; ++cq) {
        float t = lp[cq];
        t += __shfl_xor(t, 16, 64);
        t += __shfl_xor(t, 32, 64);
        lp[cq] = t;
    }
    if (lane < 16)
        #pragma unroll
        for (int cq = 0; cq < 4; ++cq)
            LDSl[w][cq][lane] = lp[cq];

    // cross-wave O reduction + normalize + store: 2 rounds x 2 q-tiles (512 threads)
    #pragma unroll
    for (int rr = 0; rr < 2; ++rr) {
        #pragma unroll
        for (int hh = 0; hh < 2; ++hh)
            #pragma unroll
            for (int cd = 0; cd < 4; ++cd)
                *reinterpret_cast<f32x4*>(&LDSf[w][hh][l16][cd * 16 + quad * 4]) = o[cd][rr * 2 + hh];
        __syncthreads();
        {
            const int hh = tid >> 8;
            const int cq = rr * 2 + hh;
            const int ql = (tid >> 4) & 15;
            const int d4 = (tid & 15) << 2;
            f32x4 acc = {};
            #pragma unroll
            for (int w2 = 0; w2 < 8; ++w2)
                acc += *reinterpret_cast<const f32x4*>(&LDSf[w2][hh][ql][d4]);
            float lq = 0.f;
            #pragma unroll
            for (int w2 = 0; w2 < 8; ++w2)
                lq += LDSl[w2][cq][ql];
            f32x4 res = acc * (1.0f / lq);
            *reinterpret_cast<f32x4*>(&out[((size_t)(b * SEQ + qt * 64 + cq * 16 + ql)) * DK + d4]) = res;
        }
        __syncthreads();
    }
}

extern "C" void kernel_launch(void* const* d_in, const int* in_sizes, int n_in,
                              void* d_out, int out_size, void* d_ws, size_t ws_size,
                              hipStream_t stream) {
    const float* input1 = (const float*)d_in[0];
    const float* input2 = (const float*)d_in[1];
    const float* Wq = (const float*)d_in[2];
    const float* bq = (const float*)d_in[3];
    const float* Wk = (const float*)d_in[4];
    const float* bk = (const float*)d_in[5];
    const float* Wv = (const float*)d_in[6];
    const float* bv = (const float*)d_in[7];
    float* out = (float*)d_out;

    char* ws = (char*)d_ws;
    unsigned short* wtq = (unsigned short*)(ws + 0);
    unsigned short* wtk = (unsigned short*)(ws + 131072);
    unsigned short* wtv = (unsigned short*)(ws + 262144);
    unsigned short* Qw  = (unsigned short*)(ws + 393216);
    unsigned short* Kw  = (unsigned short*)(ws + 2490368);
    unsigned short* Vtw = (unsigned short*)(ws + 4587520);

    wt_kernel<<<dim3(16, 3), 256, 0, stream>>>(Wq, Wk, Wv, wtq, wtk, wtv);
    proj_kernel<<<dim3(256, 2), 256, 0, stream>>>(input2, input1, wtq, wtk, wtv,
                                                  bq, bk, bv, Qw, Kw, Vtw);
    attn_kernel<<<dim3(256), 512, 0, stream>>>(Qw, Kw, Vtw, out);
}